// Round 5
// baseline (123.808 us; speedup 1.0000x reference)
//
#include <hip/hip_runtime.h>

// Multi-scale gradient-difference loss as line-parallel reductions.
// R11: R10 structure (verified 106.5us) minus ALL atomics and minus the
// memset dispatch. Mechanism ledger: hot-line f64 atomics cost ~20us (R10
// striping won 128->106.5); per-block agent-scope fences cost ~35us (R8/R9);
// grid-wide spin barriers cost ~150us (R7). This round: pass1 blocks write
// their 5 partials to a PRIVATE 128B slot (plain stores -- no RMW, no
// serialization, no zero-init, so the memset dispatch and its boundary go
// away: 4 dispatches -> 3). pass2 re-derives S1/S2 by a thread-parallel
// 2046-slot sum in its prologue (~0.3us, L2-hot, redundant per block but
// cheap); final_kernel (256 thr) reduces all 12 slot streams.
// Pre-committed read: <=95us confirms boundary+atomic theory; ~flat means
// the residual is the scattered V/diag stage gather -> next is packed-stage.

#define NSCALES 67
#define IMG_H 256
#define IMG_W 256
#define NPIX 65536
#define NLINES 2046          // 512 rows (H) + 512 cols (V) + 1022 diagonals (D)
#define LMAX_PAD 320         // 256 positions + 64 zero pad (max tap index 318)

// ws layout (doubles), no zero-init required (every cell written each run):
//  slot1[id][16] at ws + id*16 : [b*8+q], q: 0=S1 1=S2 2=posCnt 3=sumAbsPrd
//                                4=roiSum (0 unless H row), 5..7 pad
//                                (other batch's 8 cells written as 0)
//  slot2[id][2]  at ws + 32768 + id*2 : {T1_b0, T1_b1} (other batch = 0)

#define SLOT2_BASE 32768

__device__ __forceinline__ double wave_red(double v) {
#pragma unroll
  for (int o = 32; o > 0; o >>= 1) v += __shfl_down(v, o, 64);
  return v;
}

__device__ __forceinline__ void decode_line(int id, int& b, int& base, int& stride, int& L) {
  if (id < 512) {                      // horizontal row
    b = id >> 8; int y = id & 255;
    base = y * IMG_W; stride = 1; L = IMG_W;
  } else if (id < 1024) {              // vertical column
    int t = id - 512; b = t >> 8;
    base = t & 255; stride = IMG_W; L = IMG_H;
  } else {                             // diagonal c = x - y in [-255,255]
    int t = id - 1024; b = (t >= 511) ? 1 : 0;
    int d = t - b * 511; int c = d - 255;
    int ac = (c < 0) ? -c : c;
    base = (c < 0) ? (-c) * IMG_W : c;
    stride = IMG_W + 1; L = 256 - ac;
  }
}

// #scales valid for quarter q (centers [64q, 64q+63]): s = 1+3k <= min(L-1-64q, 199)
__device__ __forceinline__ int scale_count(int L, int q) {
  int rem = L - 1 - (q << 6);
  int kcnt = (rem >= 1) ? ((rem - 1) / 3 + 1) : 0;
  return (kcnt > NSCALES) ? NSCALES : kcnt;
}

// Stage line; returns this tid's ROI value (position tid) for the ROI sum.
__device__ __forceinline__ float stage_line(
    const float* __restrict__ Pred, const float* __restrict__ GT,
    const float* __restrict__ ROI, int b, int base, int stride, int L,
    int tid, float4* bufA, float4* bufB) {
  const float* P = Pred + b * (3 * NPIX);
  const float* G = GT + b * (3 * NPIX);
  const float* R = ROI + b * NPIX;
  float r = 0.f, p0 = 0.f, p1 = 0.f, p2 = 0.f, g0 = 0.f, g1 = 0.f, g2 = 0.f;
  if (tid < L) {
    int a = base + tid * stride;
    r = R[a];
    p0 = P[a]; p1 = P[a + NPIX]; p2 = P[a + 2 * NPIX];
    g0 = G[a]; g1 = G[a + NPIX]; g2 = G[a + 2 * NPIX];
  }
  bufA[tid] = make_float4(r, p0, p1, p2);
  bufB[tid] = make_float4(g0, g1, g2, 0.f);
  if (tid < LMAX_PAD - 256) {
    bufA[256 + tid] = make_float4(0.f, 0.f, 0.f, 0.f);
    bufB[256 + tid] = make_float4(0.f, 0.f, 0.f, 0.f);
  }
  __syncthreads();
  return r;
}

extern "C" __global__ void __launch_bounds__(256, 8) pass1_kernel(
    const float* __restrict__ Pred, const float* __restrict__ GT,
    const float* __restrict__ ROI, double* __restrict__ ws) {
  __shared__ float4 bufA[LMAX_PAD];    // {r, p0, p1, p2}
  __shared__ float4 bufB[LMAX_PAD];    // {g0, g1, g2, 0}
  __shared__ double red[4][5];
  const int id = blockIdx.x;
  const int tid = threadIdx.x;
  const int wid = tid >> 6, lane = tid & 63;

  int b, base, stride, L;
  decode_line(id, b, base, stride, L);
  float stg_r = stage_line(Pred, GT, ROI, b, base, stride, L, tid, bufA, bufB);

  float f1 = 0.f, f2 = 0.f, fp = 0.f;
  int pci = 0;
  int P = 0;                            // task prefix
  for (int q = 0; q < 4; ++q) {
    const int Kq = scale_count(L, q);
    int k = (wid - P) & 3;              // round-robin task deal across 4 waves
    if (k < Kq) {
      const int c = (q << 6) + lane;
      const float4 cA = bufA[c];
      const float4 cB = bufB[c];
      const float cr = cA.x, cp0 = cA.y, cp1 = cA.z, cp2 = cA.w;
      const float cg0 = cB.x, cg1 = cB.y, cg2 = cB.z;
      const float4* tA = &bufA[c + 1 + 3 * k];
      const float4* tB = &bufB[c + 1 + 3 * k];
#pragma unroll 2
      for (; k < Kq; k += 4) {
        float4 t0 = tA[0];
        float4 t1 = tB[0];
        tA += 12; tB += 12;             // s += 12
        float rr = cr * t0.x;
#define L1BODY(cp, cg, tp, tg)                                   \
        {                                                        \
          float dP = rr * (cp - tp);                             \
          float dG = rr * (cg - tg);                             \
          float qq = dP * __builtin_amdgcn_rcpf(dG + 1e-5f);     \
          float aG = fabsf(dG);                                  \
          f1 += fmaxf(aG * qq, 0.f);                             \
          if (qq > 0.f) f2 += aG;                                \
          if (dG > 0.f) pci++;                                   \
          fp += fabsf(dP);                                       \
        }
        L1BODY(cp0, cg0, t0.y, t1.x)
        L1BODY(cp1, cg1, t0.z, t1.y)
        L1BODY(cp2, cg2, t0.w, t1.z)
#undef L1BODY
      }
    }
    P += Kq;
  }

  double w0 = wave_red((double)f1);
  double w1 = wave_red((double)f2);
  double w2 = wave_red((double)pci);
  double w3 = wave_red((double)fp);
  double w4 = wave_red((double)stg_r);  // ROI partial: position tid, once/block
  if (lane == 0) {
    red[wid][0] = w0; red[wid][1] = w1; red[wid][2] = w2;
    red[wid][3] = w3; red[wid][4] = w4;
  }
  __syncthreads();
  // private 128B slot, plain stores: no RMW, no zero-init, no contention
  if (tid < 16) {
    const int q = tid & 7, tb = tid >> 3;
    double v = 0.0;
    if (tb == b && q < 5) {
      v = red[0][q] + red[1][q] + red[2][q] + red[3][q];
      if (q == 4 && id >= 512) v = 0.0; // ROI counted from H rows only
    }
    ws[(size_t)id * 16 + tid] = v;
  }
}

extern "C" __global__ void __launch_bounds__(256, 8) pass2_kernel(
    const float* __restrict__ Pred, const float* __restrict__ GT,
    const float* __restrict__ ROI, double* __restrict__ ws) {
  __shared__ float4 bufA[LMAX_PAD];
  __shared__ float4 bufB[LMAX_PAD];
  __shared__ double red[4];
  __shared__ double pre[4][4];
  __shared__ float s_invC[2];
  const int id = blockIdx.x;
  const int tid = threadIdx.x;
  const int wid = tid >> 6, lane = tid & 63;

  int b, base, stride, L;
  decode_line(id, b, base, stride, L);

  // prologue: thread-parallel slot sum -> S1,S2 per batch (L2-hot, ~0.3us)
  double a0 = 0.0, a1 = 0.0, a2 = 0.0, a3 = 0.0;
  for (int j = tid; j < NLINES; j += 256) {
    const double* s = ws + (size_t)j * 16;
    a0 += s[0]; a1 += s[1]; a2 += s[8]; a3 += s[9];
  }
  a0 = wave_red(a0); a1 = wave_red(a1); a2 = wave_red(a2); a3 = wave_red(a3);
  if (lane == 0) {
    pre[wid][0] = a0; pre[wid][1] = a1; pre[wid][2] = a2; pre[wid][3] = a3;
  }
  __syncthreads();
  if (tid < 2) {
    double S1 = pre[0][2 * tid] + pre[1][2 * tid] + pre[2][2 * tid] + pre[3][2 * tid];
    double S2 = pre[0][2 * tid + 1] + pre[1][2 * tid + 1] + pre[2][2 * tid + 1] + pre[3][2 * tid + 1];
    float cc = (float)(S1 / (S2 + 1e-4));
    s_invC[tid] = (cc > 1e-4f) ? (float)(1.0 / (double)cc) : 1.0f;
  }
  stage_line(Pred, GT, ROI, b, base, stride, L, tid, bufA, bufB);  // has barrier

  const float invC = s_invC[b];
  float f = 0.f;
  int P = 0;
  for (int q = 0; q < 4; ++q) {
    const int Kq = scale_count(L, q);
    int k = (wid - P) & 3;
    if (k < Kq) {
      const int c = (q << 6) + lane;
      const float4 cA = bufA[c];
      const float4 cB = bufB[c];
      const float cr = cA.x, cp0 = cA.y, cp1 = cA.z, cp2 = cA.w;
      const float cg0 = cB.x, cg1 = cB.y, cg2 = cB.z;
      const float4* tA = &bufA[c + 1 + 3 * k];
      const float4* tB = &bufB[c + 1 + 3 * k];
#pragma unroll 2
      for (; k < Kq; k += 4) {
        float4 t0 = tA[0];
        float4 t1 = tB[0];
        tA += 12; tB += 12;
        float rr = cr * t0.x;
        // |difGT - difPrd/c| = rr * |(g-gt) - (p-pt)*invC|   (rr in {0,1})
        f += rr * fabsf((cg0 - t1.x) - (cp0 - t0.y) * invC);
        f += rr * fabsf((cg1 - t1.y) - (cp1 - t0.z) * invC);
        f += rr * fabsf((cg2 - t1.z) - (cp2 - t0.w) * invC);
      }
    }
    P += Kq;
  }
  double t = wave_red((double)f);
  if (lane == 0) red[wid] = t;
  __syncthreads();
  if (tid < 2) {                        // private slot, batch-separated
    double v = (tid == b) ? (red[0] + red[1] + red[2] + red[3]) : 0.0;
    ws[SLOT2_BASE + (size_t)id * 2 + tid] = v;
  }
}

extern "C" __global__ void __launch_bounds__(256) final_kernel(
    const double* __restrict__ ws, float* __restrict__ out) {
  __shared__ double acc[4][12];
  const int tid = threadIdx.x;
  const int wid = tid >> 6, lane = tid & 63;
  double v[12];
#pragma unroll
  for (int i = 0; i < 12; ++i) v[i] = 0.0;
  for (int j = tid; j < NLINES; j += 256) {
    const double* s = ws + (size_t)j * 16;
    v[0] += s[0]; v[1] += s[1]; v[2] += s[2]; v[3] += s[3]; v[4] += s[4];
    v[5] += s[8]; v[6] += s[9]; v[7] += s[10]; v[8] += s[11]; v[9] += s[12];
    const double* t = ws + SLOT2_BASE + (size_t)j * 2;
    v[10] += t[0]; v[11] += t[1];
  }
#pragma unroll
  for (int i = 0; i < 12; ++i) {
    double r = wave_red(v[i]);
    if (lane == 0) acc[wid][i] = r;
  }
  __syncthreads();
  if (tid == 0) {
    double loss = 0.0;
    for (int b = 0; b < 2; ++b) {
      const int o = b * 5;
      double S1 = acc[0][o] + acc[1][o] + acc[2][o] + acc[3][o];
      double S2 = acc[0][o + 1] + acc[1][o + 1] + acc[2][o + 1] + acc[3][o + 1];
      double PC = acc[0][o + 2] + acc[1][o + 2] + acc[2][o + 2] + acc[3][o + 2];
      double SP = acc[0][o + 3] + acc[1][o + 3] + acc[2][o + 3] + acc[3][o + 3];
      double RS = acc[0][o + 4] + acc[1][o + 4] + acc[2][o + 4] + acc[3][o + 4];
      double T1 = acc[0][10 + b] + acc[1][10 + b] + acc[2][10 + b] + acc[3][10 + b];
      float cc = (float)(S1 / (S2 + 1e-4));
      out[1 + b] = cc;                  // NormConst
      double term1 = (cc > 1e-4f) ? T1 / (603.0 * 65536.0) : 0.0;
      float meanPrd = (float)(SP / PC);
      bool big = RS > 200.0;
      float t2 = (big && meanPrd > 30.f && cc > 10.f) ? (meanPrd - 30.f) : 0.f;
      float fact = 0.1f / (cc + 0.001f);
      float t3 = (big && meanPrd < 2.f && cc < 0.1f) ? (0.2f - meanPrd) * fact : 0.f;
      loss += term1 + (double)(t2 + t3);
    }
    out[0] = (float)loss;
  }
}

extern "C" void kernel_launch(void* const* d_in, const int* in_sizes, int n_in,
                              void* d_out, int out_size, void* d_ws, size_t ws_size,
                              hipStream_t stream) {
  (void)in_sizes; (void)n_in; (void)out_size; (void)ws_size;
  const float* Pred = (const float*)d_in[0];
  const float* GT = (const float*)d_in[1];
  const float* ROI = (const float*)d_in[2];
  float* out = (float*)d_out;
  double* ws = (double*)d_ws;

  // no memset: every slot cell is written by its owning block each run
  hipLaunchKernelGGL(pass1_kernel, dim3(NLINES), dim3(256), 0, stream,
                     Pred, GT, ROI, ws);
  hipLaunchKernelGGL(pass2_kernel, dim3(NLINES), dim3(256), 0, stream,
                     Pred, GT, ROI, ws);
  hipLaunchKernelGGL(final_kernel, dim3(1), dim3(256), 0, stream, ws, out);
}

// Round 6
// 118.285 us; speedup vs baseline: 1.0467x; 1.0467x over previous
//
#include <hip/hip_runtime.h>

// Multi-scale gradient-difference loss as line-parallel reductions.
// R12: R10 champion structure (striped atomics + tiny memset + 4 dispatches,
// verified 106.5us) with ONE lever: 2 lines per 512-thread block.
// Mechanism ledger: grid-spin barrier +150us (R7); per-block agent fence
// ~+35us (R8/R9); halved residency ~2x (R8); hot-line atomics +20us (R10
// fixed); per-block redundant slot reduction +17us (R11). This round:
// 1023 blocks x 8 waves (same 8184 waves = full residency), block handles
// lines (id, id+1023). Per-block fixed costs (stage barrier, epilogue,
// dispatch ramp) paid 1023x not 2046x; task dealing is 8-way over the
// combined task list -> ragged tail per block ~halves. Separate statically-
// named accumulator sets per line (rule: no runtime-indexed reg arrays);
// each line's sums land in its own batch's striped cells.

#define NSCALES 67
#define IMG_H 256
#define IMG_W 256
#define NPIX 65536
#define NLINES 2046          // 512 rows (H) + 512 cols (V) + 1022 diagonals (D)
#define LMAX_PAD 320         // 256 positions + 64 zero pad (max tap index 318)
#define GRID 1023            // block i handles lines i and i+1023

// ws layout (doubles), accumulators striped 8x by s = blockIdx & 7:
//  ACC(q,b,s) = 32 + s*64 + q*16 + b*8   q: 0=S1 1=S2 2=posCnt 3=sumAbsPrd
//  ROI(b,s)   = 544 + s*8 + b
//  T1(b,s)    = 640 + s*8 + b
// memset covers doubles [0, 704).

#define ACC_OFF(q, b, s) (32 + (s) * 64 + (q) * 16 + (b) * 8)
#define ROI_OFF(b, s) (544 + (s) * 8 + (b))
#define T1_OFF(b, s) (640 + (s) * 8 + (b))

__device__ __forceinline__ double wave_red(double v) {
#pragma unroll
  for (int o = 32; o > 0; o >>= 1) v += __shfl_down(v, o, 64);
  return v;
}

__device__ __forceinline__ void decode_line(int id, int& b, int& base, int& stride, int& L) {
  if (id < 512) {                      // horizontal row
    b = id >> 8; int y = id & 255;
    base = y * IMG_W; stride = 1; L = IMG_W;
  } else if (id < 1024) {              // vertical column
    int t = id - 512; b = t >> 8;
    base = t & 255; stride = IMG_W; L = IMG_H;
  } else {                             // diagonal c = x - y in [-255,255]
    int t = id - 1024; b = (t >= 511) ? 1 : 0;
    int d = t - b * 511; int c = d - 255;
    int ac = (c < 0) ? -c : c;
    base = (c < 0) ? (-c) * IMG_W : c;
    stride = IMG_W + 1; L = 256 - ac;
  }
}

// #scales valid for quarter q (centers [64q, 64q+63]): s = 1+3k <= min(L-1-64q, 199)
__device__ __forceinline__ int scale_count(int L, int q) {
  int rem = L - 1 - (q << 6);
  int kcnt = (rem >= 1) ? ((rem - 1) / 3 + 1) : 0;
  return (kcnt > NSCALES) ? NSCALES : kcnt;
}

// Stage this thread's line element into its line's LDS buffers.
// g = which line (0/1), lt = position 0..255. Returns ROI value at lt.
__device__ __forceinline__ float stage2(
    const float* __restrict__ Pred, const float* __restrict__ GT,
    const float* __restrict__ ROI, int b, int base, int stride, int L,
    int g, int lt, float4 (*bufA)[LMAX_PAD], float4 (*bufB)[LMAX_PAD]) {
  const float* P = Pred + b * (3 * NPIX);
  const float* G = GT + b * (3 * NPIX);
  const float* R = ROI + b * NPIX;
  float r = 0.f, p0 = 0.f, p1 = 0.f, p2 = 0.f, g0 = 0.f, g1 = 0.f, g2 = 0.f;
  if (lt < L) {
    int a = base + lt * stride;
    r = R[a];
    p0 = P[a]; p1 = P[a + NPIX]; p2 = P[a + 2 * NPIX];
    g0 = G[a]; g1 = G[a + NPIX]; g2 = G[a + 2 * NPIX];
  }
  bufA[g][lt] = make_float4(r, p0, p1, p2);
  bufB[g][lt] = make_float4(g0, g1, g2, 0.f);
  if (lt < LMAX_PAD - 256) {
    bufA[g][256 + lt] = make_float4(0.f, 0.f, 0.f, 0.f);
    bufB[g][256 + lt] = make_float4(0.f, 0.f, 0.f, 0.f);
  }
  return r;
}

#define L1BODY(cp, cg, tp, tg, F1, F2, PCI, FP)                \
  {                                                            \
    float dP = rr * (cp - tp);                                 \
    float dG = rr * (cg - tg);                                 \
    float qq = dP * __builtin_amdgcn_rcpf(dG + 1e-5f);         \
    float aG = fabsf(dG);                                      \
    F1 += fmaxf(aG * qq, 0.f);                                 \
    if (qq > 0.f) F2 += aG;                                    \
    if (dG > 0.f) PCI++;                                       \
    FP += fabsf(dP);                                           \
  }

extern "C" __global__ void __launch_bounds__(512, 8) pass1_kernel(
    const float* __restrict__ Pred, const float* __restrict__ GT,
    const float* __restrict__ ROI, double* __restrict__ ws) {
  __shared__ float4 bufA[2][LMAX_PAD];  // {r, p0, p1, p2} per line
  __shared__ float4 bufB[2][LMAX_PAD];  // {g0, g1, g2, 0}
  __shared__ double red[8][9];          // [wave][0..4 lineA, 5..8 lineB]
  const int id = blockIdx.x;
  const int tid = threadIdx.x;
  const int wid = tid >> 6, lane = tid & 63;
  const int g = tid >> 8, lt = tid & 255;

  int bA, baseA, strideA, LA;
  int bB, baseB, strideB, LB;
  decode_line(id, bA, baseA, strideA, LA);
  decode_line(id + GRID, bB, baseB, strideB, LB);

  const int myb = g ? bB : bA;
  const int mybase = g ? baseB : baseA;
  const int mystride = g ? strideB : strideA;
  const int myL = g ? LB : LA;
  float r = stage2(Pred, GT, ROI, myb, mybase, mystride, myL, g, lt, bufA, bufB);
  // ROI contribution: H rows only (lineA when id<512; lineB is never H)
  float roi_r = (g == 0 && id < 512) ? r : 0.f;
  __syncthreads();

  float f1 = 0.f, f2 = 0.f, fp = 0.f; int pci = 0;   // line A accum
  float h1 = 0.f, h2 = 0.f, hp = 0.f; int qci = 0;   // line B accum
  int P = 0;                            // prefix over the 8 combined runs
  // ---- runs 0..3: line A quarters ----
  for (int q = 0; q < 4; ++q) {
    const int Kq = scale_count(LA, q);
    int k = (wid - P) & 7;              // 8-way round-robin deal
    if (k < Kq) {
      const int c = (q << 6) + lane;
      const float4 cA = bufA[0][c];
      const float4 cB = bufB[0][c];
      const float cr = cA.x, cp0 = cA.y, cp1 = cA.z, cp2 = cA.w;
      const float cg0 = cB.x, cg1 = cB.y, cg2 = cB.z;
      const float4* tA = &bufA[0][c + 1 + 3 * k];
      const float4* tB = &bufB[0][c + 1 + 3 * k];
#pragma unroll 2
      for (; k < Kq; k += 8) {
        float4 t0 = tA[0];
        float4 t1 = tB[0];
        tA += 24; tB += 24;             // s += 24
        float rr = cr * t0.x;
        L1BODY(cp0, cg0, t0.y, t1.x, f1, f2, pci, fp)
        L1BODY(cp1, cg1, t0.z, t1.y, f1, f2, pci, fp)
        L1BODY(cp2, cg2, t0.w, t1.z, f1, f2, pci, fp)
      }
    }
    P += Kq;
  }
  // ---- runs 4..7: line B quarters ----
  for (int q = 0; q < 4; ++q) {
    const int Kq = scale_count(LB, q);
    int k = (wid - P) & 7;
    if (k < Kq) {
      const int c = (q << 6) + lane;
      const float4 cA = bufA[1][c];
      const float4 cB = bufB[1][c];
      const float cr = cA.x, cp0 = cA.y, cp1 = cA.z, cp2 = cA.w;
      const float cg0 = cB.x, cg1 = cB.y, cg2 = cB.z;
      const float4* tA = &bufA[1][c + 1 + 3 * k];
      const float4* tB = &bufB[1][c + 1 + 3 * k];
#pragma unroll 2
      for (; k < Kq; k += 8) {
        float4 t0 = tA[0];
        float4 t1 = tB[0];
        tA += 24; tB += 24;
        float rr = cr * t0.x;
        L1BODY(cp0, cg0, t0.y, t1.x, h1, h2, qci, hp)
        L1BODY(cp1, cg1, t0.z, t1.y, h1, h2, qci, hp)
        L1BODY(cp2, cg2, t0.w, t1.z, h1, h2, qci, hp)
      }
    }
    P += Kq;
  }

  double vA0 = wave_red((double)f1);
  double vA1 = wave_red((double)f2);
  double vA2 = wave_red((double)pci);
  double vA3 = wave_red((double)fp);
  double vA4 = wave_red((double)roi_r);
  double vB0 = wave_red((double)h1);
  double vB1 = wave_red((double)h2);
  double vB2 = wave_red((double)qci);
  double vB3 = wave_red((double)hp);
  if (lane == 0) {
    red[wid][0] = vA0; red[wid][1] = vA1; red[wid][2] = vA2;
    red[wid][3] = vA3; red[wid][4] = vA4;
    red[wid][5] = vB0; red[wid][6] = vB1; red[wid][7] = vB2;
    red[wid][8] = vB3;
  }
  __syncthreads();
  const int s = id & 7;                 // 8-way stripe
  if (tid < 4) {
    double v = 0.0;
#pragma unroll
    for (int w = 0; w < 8; ++w) v += red[w][tid];
    unsafeAtomicAdd(&ws[ACC_OFF(tid, bA, s)], v);
  } else if (tid >= 8 && tid < 12) {
    const int q = tid - 8;
    double v = 0.0;
#pragma unroll
    for (int w = 0; w < 8; ++w) v += red[w][5 + q];
    unsafeAtomicAdd(&ws[ACC_OFF(q, bB, s)], v);
  }
  if (tid == 16 && id < 512) {          // only waves 0-3 staged H-row ROI
    double v = red[0][4] + red[1][4] + red[2][4] + red[3][4];
    unsafeAtomicAdd(&ws[ROI_OFF(bA, s)], v);
  }
}

extern "C" __global__ void __launch_bounds__(512, 8) pass2_kernel(
    const float* __restrict__ Pred, const float* __restrict__ GT,
    const float* __restrict__ ROI, double* __restrict__ ws) {
  __shared__ float4 bufA[2][LMAX_PAD];
  __shared__ float4 bufB[2][LMAX_PAD];
  __shared__ double red[8][2];
  __shared__ float s_invC[2];
  const int id = blockIdx.x;
  const int tid = threadIdx.x;
  const int wid = tid >> 6, lane = tid & 63;
  const int g = tid >> 8, lt = tid & 255;

  int bA, baseA, strideA, LA;
  int bB, baseB, strideB, LB;
  decode_line(id, bA, baseA, strideA, LA);
  decode_line(id + GRID, bB, baseB, strideB, LB);

  if (tid < 2) {                        // invC per batch from striped pass1
    double S1 = 0.0, S2 = 0.0;          // sums (coherent across launch bound)
#pragma unroll
    for (int st = 0; st < 8; ++st) {
      S1 += ws[ACC_OFF(0, tid, st)];
      S2 += ws[ACC_OFF(1, tid, st)];
    }
    float cc = (float)(S1 / (S2 + 1e-4));
    s_invC[tid] = (cc > 1e-4f) ? (float)(1.0 / (double)cc) : 1.0f;
  }
  const int myb = g ? bB : bA;
  const int mybase = g ? baseB : baseA;
  const int mystride = g ? strideB : strideA;
  const int myL = g ? LB : LA;
  stage2(Pred, GT, ROI, myb, mybase, mystride, myL, g, lt, bufA, bufB);
  __syncthreads();

  const float invCA = s_invC[bA];
  const float invCB = s_invC[bB];
  float fA = 0.f, fB = 0.f;
  int P = 0;
  for (int q = 0; q < 4; ++q) {
    const int Kq = scale_count(LA, q);
    int k = (wid - P) & 7;
    if (k < Kq) {
      const int c = (q << 6) + lane;
      const float4 cA = bufA[0][c];
      const float4 cB = bufB[0][c];
      const float cr = cA.x, cp0 = cA.y, cp1 = cA.z, cp2 = cA.w;
      const float cg0 = cB.x, cg1 = cB.y, cg2 = cB.z;
      const float4* tA = &bufA[0][c + 1 + 3 * k];
      const float4* tB = &bufB[0][c + 1 + 3 * k];
#pragma unroll 2
      for (; k < Kq; k += 8) {
        float4 t0 = tA[0];
        float4 t1 = tB[0];
        tA += 24; tB += 24;
        float rr = cr * t0.x;
        // |difGT - difPrd/c| = rr * |(g-gt) - (p-pt)*invC|   (rr in {0,1})
        fA += rr * fabsf((cg0 - t1.x) - (cp0 - t0.y) * invCA);
        fA += rr * fabsf((cg1 - t1.y) - (cp1 - t0.z) * invCA);
        fA += rr * fabsf((cg2 - t1.z) - (cp2 - t0.w) * invCA);
      }
    }
    P += Kq;
  }
  for (int q = 0; q < 4; ++q) {
    const int Kq = scale_count(LB, q);
    int k = (wid - P) & 7;
    if (k < Kq) {
      const int c = (q << 6) + lane;
      const float4 cA = bufA[1][c];
      const float4 cB = bufB[1][c];
      const float cr = cA.x, cp0 = cA.y, cp1 = cA.z, cp2 = cA.w;
      const float cg0 = cB.x, cg1 = cB.y, cg2 = cB.z;
      const float4* tA = &bufA[1][c + 1 + 3 * k];
      const float4* tB = &bufB[1][c + 1 + 3 * k];
#pragma unroll 2
      for (; k < Kq; k += 8) {
        float4 t0 = tA[0];
        float4 t1 = tB[0];
        tA += 24; tB += 24;
        float rr = cr * t0.x;
        fB += rr * fabsf((cg0 - t1.x) - (cp0 - t0.y) * invCB);
        fB += rr * fabsf((cg1 - t1.y) - (cp1 - t0.z) * invCB);
        fB += rr * fabsf((cg2 - t1.z) - (cp2 - t0.w) * invCB);
      }
    }
    P += Kq;
  }
  double tA_ = wave_red((double)fA);
  double tB_ = wave_red((double)fB);
  if (lane == 0) { red[wid][0] = tA_; red[wid][1] = tB_; }
  __syncthreads();
  if (tid < 2) {
    double v = 0.0;
#pragma unroll
    for (int w = 0; w < 8; ++w) v += red[w][tid];
    unsafeAtomicAdd(&ws[T1_OFF(tid == 0 ? bA : bB, id & 7)], v);
  }
}

extern "C" __global__ void __launch_bounds__(64) final_kernel(
    const double* __restrict__ ws, float* __restrict__ out) {
  if (threadIdx.x == 0) {
    double loss = 0.0;
    for (int b = 0; b < 2; ++b) {
      double S1 = 0.0, S2 = 0.0, PC = 0.0, SP = 0.0, RS = 0.0, T1 = 0.0;
      for (int st = 0; st < 8; ++st) {
        S1 += ws[ACC_OFF(0, b, st)];
        S2 += ws[ACC_OFF(1, b, st)];
        PC += ws[ACC_OFF(2, b, st)];
        SP += ws[ACC_OFF(3, b, st)];
        RS += ws[ROI_OFF(b, st)];
        T1 += ws[T1_OFF(b, st)];
      }
      float cc = (float)(S1 / (S2 + 1e-4));
      out[1 + b] = cc;                  // NormConst
      double term1 = (cc > 1e-4f) ? T1 / (603.0 * 65536.0) : 0.0;
      float meanPrd = (float)(SP / PC);
      bool big = RS > 200.0;
      float t2 = (big && meanPrd > 30.f && cc > 10.f) ? (meanPrd - 30.f) : 0.f;
      float fact = 0.1f / (cc + 0.001f);
      float t3 = (big && meanPrd < 2.f && cc < 0.1f) ? (0.2f - meanPrd) * fact : 0.f;
      loss += term1 + (double)(t2 + t3);
    }
    out[0] = (float)loss;
  }
}

extern "C" void kernel_launch(void* const* d_in, const int* in_sizes, int n_in,
                              void* d_out, int out_size, void* d_ws, size_t ws_size,
                              hipStream_t stream) {
  (void)in_sizes; (void)n_in; (void)out_size; (void)ws_size;
  const float* Pred = (const float*)d_in[0];
  const float* GT = (const float*)d_in[1];
  const float* ROI = (const float*)d_in[2];
  float* out = (float*)d_out;
  double* ws = (double*)d_ws;

  hipMemsetAsync(d_ws, 0, 704 * sizeof(double), stream);  // striped accums
  hipLaunchKernelGGL(pass1_kernel, dim3(GRID), dim3(512), 0, stream,
                     Pred, GT, ROI, ws);
  hipLaunchKernelGGL(pass2_kernel, dim3(GRID), dim3(512), 0, stream,
                     Pred, GT, ROI, ws);
  hipLaunchKernelGGL(final_kernel, dim3(1), dim3(64), 0, stream, ws, out);
}

// Round 7
// 106.559 us; speedup vs baseline: 1.1619x; 1.1100x over previous
//
#include <hip/hip_runtime.h>

// Multi-scale gradient-difference loss as line-parallel reductions.
// R13: R10 champion structure EXACTLY (2046x256 blocks, 4-way wave deal,
// 8x-striped atomics, 4 dispatches; verified 106.5us) with ONE change:
// inner bodies pack channels 0/1 into float2 ext_vectors so clang emits
// dual-FP32 v_pk_*_f32 (gfx950 full-rate f32 is packed; scalar is half
// rate). R12 measured pass1 VALUBusy ~60% with 0 bank conflicts and L2-
// resident inputs -> passes are issue-bound; cutting VALU slots ~30% is
// the remaining lever. Channel 2 + rcp/cmp/sel stay scalar.
// Mechanism ledger: grid-spin barrier +150us (R7); per-block agent fence
// ~+35us (R8/R9); halved residency ~2x (R8); hot-line atomics +20us (R10
// fixed); per-block redundant slot reduce +17us (R11); 2-line blocks +12us
// (R12).

#define NSCALES 67
#define IMG_H 256
#define IMG_W 256
#define NPIX 65536
#define NLINES 2046          // 512 rows (H) + 512 cols (V) + 1022 diagonals (D)
#define LMAX_PAD 320         // 256 positions + 64 zero pad (max tap index 318)

typedef float v2f __attribute__((ext_vector_type(2)));

// ws layout (doubles), all accumulators striped 8x by s = blockIdx & 7:
//  ACC(q,b,s) = 32 + s*64 + q*16 + b*8   q: 0=S1 1=S2 2=posCnt 3=sumAbsPrd
//  ROI(b,s)   = 544 + s*8 + b
//  T1(b,s)    = 640 + s*8 + b
// memset covers doubles [0, 704).

#define ACC_OFF(q, b, s) (32 + (s) * 64 + (q) * 16 + (b) * 8)
#define ROI_OFF(b, s) (544 + (s) * 8 + (b))
#define T1_OFF(b, s) (640 + (s) * 8 + (b))

__device__ __forceinline__ double wave_red(double v) {
#pragma unroll
  for (int o = 32; o > 0; o >>= 1) v += __shfl_down(v, o, 64);
  return v;
}

__device__ __forceinline__ v2f rcp2(v2f x) {
  v2f r;
  r.x = __builtin_amdgcn_rcpf(x.x);
  r.y = __builtin_amdgcn_rcpf(x.y);
  return r;
}

__device__ __forceinline__ void decode_line(int id, int& b, int& base, int& stride, int& L) {
  if (id < 512) {                      // horizontal row
    b = id >> 8; int y = id & 255;
    base = y * IMG_W; stride = 1; L = IMG_W;
  } else if (id < 1024) {              // vertical column
    int t = id - 512; b = t >> 8;
    base = t & 255; stride = IMG_W; L = IMG_H;
  } else {                             // diagonal c = x - y in [-255,255]
    int t = id - 1024; b = (t >= 511) ? 1 : 0;
    int d = t - b * 511; int c = d - 255;
    int ac = (c < 0) ? -c : c;
    base = (c < 0) ? (-c) * IMG_W : c;
    stride = IMG_W + 1; L = 256 - ac;
  }
}

// #scales valid for quarter q (centers [64q, 64q+63]): s = 1+3k <= min(L-1-64q, 199)
__device__ __forceinline__ int scale_count(int L, int q) {
  int rem = L - 1 - (q << 6);
  int kcnt = (rem >= 1) ? ((rem - 1) / 3 + 1) : 0;
  return (kcnt > NSCALES) ? NSCALES : kcnt;
}

// Stage line; returns this tid's ROI value (position tid) for the ROI sum.
__device__ __forceinline__ float stage_line(
    const float* __restrict__ Pred, const float* __restrict__ GT,
    const float* __restrict__ ROI, int b, int base, int stride, int L,
    int tid, float4* bufA, float4* bufB) {
  const float* P = Pred + b * (3 * NPIX);
  const float* G = GT + b * (3 * NPIX);
  const float* R = ROI + b * NPIX;
  float r = 0.f, p0 = 0.f, p1 = 0.f, p2 = 0.f, g0 = 0.f, g1 = 0.f, g2 = 0.f;
  if (tid < L) {
    int a = base + tid * stride;
    r = R[a];
    p0 = P[a]; p1 = P[a + NPIX]; p2 = P[a + 2 * NPIX];
    g0 = G[a]; g1 = G[a + NPIX]; g2 = G[a + 2 * NPIX];
  }
  bufA[tid] = make_float4(r, p0, p1, p2);
  bufB[tid] = make_float4(g0, g1, g2, 0.f);
  if (tid < LMAX_PAD - 256) {
    bufA[256 + tid] = make_float4(0.f, 0.f, 0.f, 0.f);
    bufB[256 + tid] = make_float4(0.f, 0.f, 0.f, 0.f);
  }
  __syncthreads();
  return r;
}

extern "C" __global__ void __launch_bounds__(256, 8) pass1_kernel(
    const float* __restrict__ Pred, const float* __restrict__ GT,
    const float* __restrict__ ROI, double* __restrict__ ws) {
  __shared__ float4 bufA[LMAX_PAD];    // {r, p0, p1, p2}
  __shared__ float4 bufB[LMAX_PAD];    // {g0, g1, g2, 0}
  __shared__ double red[4][5];
  const int id = blockIdx.x;
  const int tid = threadIdx.x;
  const int wid = tid >> 6, lane = tid & 63;

  int b, base, stride, L;
  decode_line(id, b, base, stride, L);
  float stg_r = stage_line(Pred, GT, ROI, b, base, stride, L, tid, bufA, bufB);

  v2f f1v = {0.f, 0.f}, fpv = {0.f, 0.f};
  float f1s = 0.f, fps = 0.f, f2 = 0.f;
  int pci = 0;
  int P = 0;                            // task prefix
  for (int q = 0; q < 4; ++q) {
    const int Kq = scale_count(L, q);
    int k = (wid - P) & 3;              // round-robin task deal across 4 waves
    if (k < Kq) {
      const int c = (q << 6) + lane;
      const float4 cA = bufA[c];
      const float4 cB = bufB[c];
      const float cr = cA.x;
      const v2f cp01 = {cA.y, cA.z};    // ch0/ch1 packed (dual-f32 pipe)
      const v2f cg01 = {cB.x, cB.y};
      const float cp2s = cA.w, cg2s = cB.z;
      const float4* tA = &bufA[c + 1 + 3 * k];
      const float4* tB = &bufB[c + 1 + 3 * k];
#pragma unroll 2
      for (; k < Kq; k += 4) {
        float4 t0 = tA[0];
        float4 t1 = tB[0];
        tA += 12; tB += 12;             // s += 12
        float rr = cr * t0.x;
        v2f rr2 = {rr, rr};
        // ---- packed ch0/ch1 ----
        v2f dP = (cp01 - (v2f){t0.y, t0.z}) * rr2;
        v2f dG = (cg01 - (v2f){t1.x, t1.y}) * rr2;
        v2f qq = dP * rcp2(dG + (v2f){1e-5f, 1e-5f});
        v2f aG = __builtin_elementwise_abs(dG);
        f1v += __builtin_elementwise_max(aG * qq, (v2f){0.f, 0.f});
        if (qq.x > 0.f) f2 += aG.x;
        if (qq.y > 0.f) f2 += aG.y;
        if (dG.x > 0.f) pci++;
        if (dG.y > 0.f) pci++;
        fpv += __builtin_elementwise_abs(dP);
        // ---- scalar ch2 ----
        {
          float dPs = rr * (cp2s - t0.w);
          float dGs = rr * (cg2s - t1.z);
          float qqs = dPs * __builtin_amdgcn_rcpf(dGs + 1e-5f);
          float aGs = fabsf(dGs);
          f1s += fmaxf(aGs * qqs, 0.f);
          if (qqs > 0.f) f2 += aGs;
          if (dGs > 0.f) pci++;
          fps += fabsf(dPs);
        }
      }
    }
    P += Kq;
  }

  const float f1 = (f1v.x + f1v.y) + f1s;
  const float fp = (fpv.x + fpv.y) + fps;
  double w0 = wave_red((double)f1);
  double w1 = wave_red((double)f2);
  double w2 = wave_red((double)pci);
  double w3 = wave_red((double)fp);
  double w4 = wave_red((double)stg_r);  // ROI partial: position tid, once/block
  if (lane == 0) {
    red[wid][0] = w0; red[wid][1] = w1; red[wid][2] = w2;
    red[wid][3] = w3; red[wid][4] = w4;
  }
  __syncthreads();
  const int s = id & 7;                 // 8-way stripe, own line per cell
  if (tid < 4)
    unsafeAtomicAdd(&ws[ACC_OFF(tid, b, s)],
                    red[0][tid] + red[1][tid] + red[2][tid] + red[3][tid]);
  if (tid == 4 && id < 512)             // H rows tile the image exactly once
    unsafeAtomicAdd(&ws[ROI_OFF(b, s)],
                    red[0][4] + red[1][4] + red[2][4] + red[3][4]);
}

extern "C" __global__ void __launch_bounds__(256, 8) pass2_kernel(
    const float* __restrict__ Pred, const float* __restrict__ GT,
    const float* __restrict__ ROI, double* __restrict__ ws) {
  __shared__ float4 bufA[LMAX_PAD];
  __shared__ float4 bufB[LMAX_PAD];
  __shared__ double red[4];
  __shared__ float s_invC[2];
  const int id = blockIdx.x;
  const int tid = threadIdx.x;
  const int wid = tid >> 6, lane = tid & 63;

  int b, base, stride, L;
  decode_line(id, b, base, stride, L);
  if (tid < 2) {                        // invC per batch from striped pass1
    double S1 = 0.0, S2 = 0.0;          // sums (coherent across launch bound)
#pragma unroll
    for (int st = 0; st < 8; ++st) {
      S1 += ws[ACC_OFF(0, tid, st)];
      S2 += ws[ACC_OFF(1, tid, st)];
    }
    float cc = (float)(S1 / (S2 + 1e-4));
    s_invC[tid] = (cc > 1e-4f) ? (float)(1.0 / (double)cc) : 1.0f;
  }
  stage_line(Pred, GT, ROI, b, base, stride, L, tid, bufA, bufB);

  const float invC = s_invC[b];
  const v2f invC2 = {invC, invC};
  v2f fv = {0.f, 0.f};
  float fs = 0.f;
  int P = 0;
  for (int q = 0; q < 4; ++q) {
    const int Kq = scale_count(L, q);
    int k = (wid - P) & 3;
    if (k < Kq) {
      const int c = (q << 6) + lane;
      const float4 cA = bufA[c];
      const float4 cB = bufB[c];
      const float cr = cA.x;
      const v2f cp01 = {cA.y, cA.z};
      const v2f cg01 = {cB.x, cB.y};
      const float cp2s = cA.w, cg2s = cB.z;
      const float4* tA = &bufA[c + 1 + 3 * k];
      const float4* tB = &bufB[c + 1 + 3 * k];
#pragma unroll 2
      for (; k < Kq; k += 4) {
        float4 t0 = tA[0];
        float4 t1 = tB[0];
        tA += 12; tB += 12;
        float rr = cr * t0.x;
        v2f rr2 = {rr, rr};
        // |difGT - difPrd/c| = rr * |(g-gt) - (p-pt)*invC|   (rr in {0,1})
        v2f d01 = (cg01 - (v2f){t1.x, t1.y})
                - (cp01 - (v2f){t0.y, t0.z}) * invC2;
        fv += rr2 * __builtin_elementwise_abs(d01);
        float ds = (cg2s - t1.z) - (cp2s - t0.w) * invC;
        fs += rr * fabsf(ds);
      }
    }
    P += Kq;
  }
  const float f = (fv.x + fv.y) + fs;
  double t = wave_red((double)f);
  if (lane == 0) red[wid] = t;
  __syncthreads();
  if (tid == 0)
    unsafeAtomicAdd(&ws[T1_OFF(b, id & 7)],
                    red[0] + red[1] + red[2] + red[3]);
}

extern "C" __global__ void __launch_bounds__(64) final_kernel(
    const double* __restrict__ ws, float* __restrict__ out) {
  if (threadIdx.x == 0) {
    double loss = 0.0;
    for (int b = 0; b < 2; ++b) {
      double S1 = 0.0, S2 = 0.0, PC = 0.0, SP = 0.0, RS = 0.0, T1 = 0.0;
      for (int st = 0; st < 8; ++st) {
        S1 += ws[ACC_OFF(0, b, st)];
        S2 += ws[ACC_OFF(1, b, st)];
        PC += ws[ACC_OFF(2, b, st)];
        SP += ws[ACC_OFF(3, b, st)];
        RS += ws[ROI_OFF(b, st)];
        T1 += ws[T1_OFF(b, st)];
      }
      float cc = (float)(S1 / (S2 + 1e-4));
      out[1 + b] = cc;                  // NormConst
      double term1 = (cc > 1e-4f) ? T1 / (603.0 * 65536.0) : 0.0;
      float meanPrd = (float)(SP / PC);
      bool big = RS > 200.0;
      float t2 = (big && meanPrd > 30.f && cc > 10.f) ? (meanPrd - 30.f) : 0.f;
      float fact = 0.1f / (cc + 0.001f);
      float t3 = (big && meanPrd < 2.f && cc < 0.1f) ? (0.2f - meanPrd) * fact : 0.f;
      loss += term1 + (double)(t2 + t3);
    }
    out[0] = (float)loss;
  }
}

extern "C" void kernel_launch(void* const* d_in, const int* in_sizes, int n_in,
                              void* d_out, int out_size, void* d_ws, size_t ws_size,
                              hipStream_t stream) {
  (void)in_sizes; (void)n_in; (void)out_size; (void)ws_size;
  const float* Pred = (const float*)d_in[0];
  const float* GT = (const float*)d_in[1];
  const float* ROI = (const float*)d_in[2];
  float* out = (float*)d_out;
  double* ws = (double*)d_ws;

  hipMemsetAsync(d_ws, 0, 704 * sizeof(double), stream);  // striped accums
  hipLaunchKernelGGL(pass1_kernel, dim3(NLINES), dim3(256), 0, stream,
                     Pred, GT, ROI, ws);
  hipLaunchKernelGGL(pass2_kernel, dim3(NLINES), dim3(256), 0, stream,
                     Pred, GT, ROI, ws);
  hipLaunchKernelGGL(final_kernel, dim3(1), dim3(64), 0, stream, ws, out);
}

// Round 8
// 104.649 us; speedup vs baseline: 1.1831x; 1.0183x over previous
//
#include <hip/hip_runtime.h>

// Multi-scale gradient-difference loss as line-parallel reductions.
// R14: champion R10 structure (2046x256, 4-way wave deal, 8x-striped
// atomics, 4 dispatches; 106.5us) + two numerics-exact micro levers:
//  1) posCnt via __ballot + popcount: moves ~6 VALU slots/iter (cmp+sel+add
//     x3 channels) onto the scalar pipe; pci becomes wave-uniform (lane 0
//     writes it; one fewer f64 wave_red).
//  2) #pragma unroll 4 (was 2): more outstanding ds_read_b128 across the
//     backedge to attack the ~40% stall fraction (R12: VALUBusy 60%,
//     0 bank conflicts, L2-resident inputs).
// Ledger: grid-spin barrier +150us (R7); per-block agent fence +35us
// (R8/R9); halved residency ~2x (R8); hot-line atomics +20us (R10 fixed);
// redundant per-block slot reduce +17us (R11); 2-line blocks +12us (R12);
// v2f packing +-0 (R13 -- scalarized or not binding).
// Pre-commit: delta < 3us => issue-count and backedge levers dead; declare
// structural floor.

#define NSCALES 67
#define IMG_H 256
#define IMG_W 256
#define NPIX 65536
#define NLINES 2046          // 512 rows (H) + 512 cols (V) + 1022 diagonals (D)
#define LMAX_PAD 320         // 256 positions + 64 zero pad (max tap index 318)

// ws layout (doubles), all accumulators striped 8x by s = blockIdx & 7:
//  ACC(q,b,s) = 32 + s*64 + q*16 + b*8   q: 0=S1 1=S2 2=posCnt 3=sumAbsPrd
//  ROI(b,s)   = 544 + s*8 + b
//  T1(b,s)    = 640 + s*8 + b
// memset covers doubles [0, 704).

#define ACC_OFF(q, b, s) (32 + (s) * 64 + (q) * 16 + (b) * 8)
#define ROI_OFF(b, s) (544 + (s) * 8 + (b))
#define T1_OFF(b, s) (640 + (s) * 8 + (b))

__device__ __forceinline__ double wave_red(double v) {
#pragma unroll
  for (int o = 32; o > 0; o >>= 1) v += __shfl_down(v, o, 64);
  return v;
}

__device__ __forceinline__ void decode_line(int id, int& b, int& base, int& stride, int& L) {
  if (id < 512) {                      // horizontal row
    b = id >> 8; int y = id & 255;
    base = y * IMG_W; stride = 1; L = IMG_W;
  } else if (id < 1024) {              // vertical column
    int t = id - 512; b = t >> 8;
    base = t & 255; stride = IMG_W; L = IMG_H;
  } else {                             // diagonal c = x - y in [-255,255]
    int t = id - 1024; b = (t >= 511) ? 1 : 0;
    int d = t - b * 511; int c = d - 255;
    int ac = (c < 0) ? -c : c;
    base = (c < 0) ? (-c) * IMG_W : c;
    stride = IMG_W + 1; L = 256 - ac;
  }
}

// #scales valid for quarter q (centers [64q, 64q+63]): s = 1+3k <= min(L-1-64q, 199)
__device__ __forceinline__ int scale_count(int L, int q) {
  int rem = L - 1 - (q << 6);
  int kcnt = (rem >= 1) ? ((rem - 1) / 3 + 1) : 0;
  return (kcnt > NSCALES) ? NSCALES : kcnt;
}

// Stage line; returns this tid's ROI value (position tid) for the ROI sum.
__device__ __forceinline__ float stage_line(
    const float* __restrict__ Pred, const float* __restrict__ GT,
    const float* __restrict__ ROI, int b, int base, int stride, int L,
    int tid, float4* bufA, float4* bufB) {
  const float* P = Pred + b * (3 * NPIX);
  const float* G = GT + b * (3 * NPIX);
  const float* R = ROI + b * NPIX;
  float r = 0.f, p0 = 0.f, p1 = 0.f, p2 = 0.f, g0 = 0.f, g1 = 0.f, g2 = 0.f;
  if (tid < L) {
    int a = base + tid * stride;
    r = R[a];
    p0 = P[a]; p1 = P[a + NPIX]; p2 = P[a + 2 * NPIX];
    g0 = G[a]; g1 = G[a + NPIX]; g2 = G[a + 2 * NPIX];
  }
  bufA[tid] = make_float4(r, p0, p1, p2);
  bufB[tid] = make_float4(g0, g1, g2, 0.f);
  if (tid < LMAX_PAD - 256) {
    bufA[256 + tid] = make_float4(0.f, 0.f, 0.f, 0.f);
    bufB[256 + tid] = make_float4(0.f, 0.f, 0.f, 0.f);
  }
  __syncthreads();
  return r;
}

extern "C" __global__ void __launch_bounds__(256, 8) pass1_kernel(
    const float* __restrict__ Pred, const float* __restrict__ GT,
    const float* __restrict__ ROI, double* __restrict__ ws) {
  __shared__ float4 bufA[LMAX_PAD];    // {r, p0, p1, p2}
  __shared__ float4 bufB[LMAX_PAD];    // {g0, g1, g2, 0}
  __shared__ double red[4][5];
  const int id = blockIdx.x;
  const int tid = threadIdx.x;
  const int wid = tid >> 6, lane = tid & 63;

  int b, base, stride, L;
  decode_line(id, b, base, stride, L);
  float stg_r = stage_line(Pred, GT, ROI, b, base, stride, L, tid, bufA, bufB);

  float f1 = 0.f, f2 = 0.f, fp = 0.f;
  int pci = 0;                          // wave-uniform (ballot-counted)
  int P = 0;                            // task prefix
  for (int q = 0; q < 4; ++q) {
    const int Kq = scale_count(L, q);
    int k = (wid - P) & 3;              // round-robin task deal across 4 waves
    if (k < Kq) {
      const int c = (q << 6) + lane;
      const float4 cA = bufA[c];
      const float4 cB = bufB[c];
      const float cr = cA.x, cp0 = cA.y, cp1 = cA.z, cp2 = cA.w;
      const float cg0 = cB.x, cg1 = cB.y, cg2 = cB.z;
      const float4* tA = &bufA[c + 1 + 3 * k];
      const float4* tB = &bufB[c + 1 + 3 * k];
#pragma unroll 4
      for (; k < Kq; k += 4) {
        float4 t0 = tA[0];
        float4 t1 = tB[0];
        tA += 12; tB += 12;             // s += 12
        float rr = cr * t0.x;
#define L1BODY(cp, cg, tp, tg)                                   \
        {                                                        \
          float dP = rr * (cp - tp);                             \
          float dG = rr * (cg - tg);                             \
          float qq = dP * __builtin_amdgcn_rcpf(dG + 1e-5f);     \
          float aG = fabsf(dG);                                  \
          f1 += fmaxf(aG * qq, 0.f);                             \
          if (qq > 0.f) f2 += aG;                                \
          pci += __builtin_popcountll(__ballot(dG > 0.f));       \
          fp += fabsf(dP);                                       \
        }
        L1BODY(cp0, cg0, t0.y, t1.x)
        L1BODY(cp1, cg1, t0.z, t1.y)
        L1BODY(cp2, cg2, t0.w, t1.z)
#undef L1BODY
      }
    }
    P += Kq;
  }

  double w0 = wave_red((double)f1);
  double w1 = wave_red((double)f2);
  double w3 = wave_red((double)fp);
  double w4 = wave_red((double)stg_r);  // ROI partial: position tid, once/block
  if (lane == 0) {
    red[wid][0] = w0; red[wid][1] = w1;
    red[wid][2] = (double)pci;          // wave-uniform: no shuffle reduce
    red[wid][3] = w3; red[wid][4] = w4;
  }
  __syncthreads();
  const int s = id & 7;                 // 8-way stripe, own line per cell
  if (tid < 4)
    unsafeAtomicAdd(&ws[ACC_OFF(tid, b, s)],
                    red[0][tid] + red[1][tid] + red[2][tid] + red[3][tid]);
  if (tid == 4 && id < 512)             // H rows tile the image exactly once
    unsafeAtomicAdd(&ws[ROI_OFF(b, s)],
                    red[0][4] + red[1][4] + red[2][4] + red[3][4]);
}

extern "C" __global__ void __launch_bounds__(256, 8) pass2_kernel(
    const float* __restrict__ Pred, const float* __restrict__ GT,
    const float* __restrict__ ROI, double* __restrict__ ws) {
  __shared__ float4 bufA[LMAX_PAD];
  __shared__ float4 bufB[LMAX_PAD];
  __shared__ double red[4];
  __shared__ float s_invC[2];
  const int id = blockIdx.x;
  const int tid = threadIdx.x;
  const int wid = tid >> 6, lane = tid & 63;

  int b, base, stride, L;
  decode_line(id, b, base, stride, L);
  if (tid < 2) {                        // invC per batch from striped pass1
    double S1 = 0.0, S2 = 0.0;          // sums (coherent across launch bound)
#pragma unroll
    for (int st = 0; st < 8; ++st) {
      S1 += ws[ACC_OFF(0, tid, st)];
      S2 += ws[ACC_OFF(1, tid, st)];
    }
    float cc = (float)(S1 / (S2 + 1e-4));
    s_invC[tid] = (cc > 1e-4f) ? (float)(1.0 / (double)cc) : 1.0f;
  }
  stage_line(Pred, GT, ROI, b, base, stride, L, tid, bufA, bufB);

  const float invC = s_invC[b];
  float f = 0.f;
  int P = 0;
  for (int q = 0; q < 4; ++q) {
    const int Kq = scale_count(L, q);
    int k = (wid - P) & 3;
    if (k < Kq) {
      const int c = (q << 6) + lane;
      const float4 cA = bufA[c];
      const float4 cB = bufB[c];
      const float cr = cA.x, cp0 = cA.y, cp1 = cA.z, cp2 = cA.w;
      const float cg0 = cB.x, cg1 = cB.y, cg2 = cB.z;
      const float4* tA = &bufA[c + 1 + 3 * k];
      const float4* tB = &bufB[c + 1 + 3 * k];
#pragma unroll 4
      for (; k < Kq; k += 4) {
        float4 t0 = tA[0];
        float4 t1 = tB[0];
        tA += 12; tB += 12;
        float rr = cr * t0.x;
        // |difGT - difPrd/c| = rr * |(g-gt) - (p-pt)*invC|   (rr in {0,1})
        f += rr * fabsf((cg0 - t1.x) - (cp0 - t0.y) * invC);
        f += rr * fabsf((cg1 - t1.y) - (cp1 - t0.z) * invC);
        f += rr * fabsf((cg2 - t1.z) - (cp2 - t0.w) * invC);
      }
    }
    P += Kq;
  }
  double t = wave_red((double)f);
  if (lane == 0) red[wid] = t;
  __syncthreads();
  if (tid == 0)
    unsafeAtomicAdd(&ws[T1_OFF(b, id & 7)],
                    red[0] + red[1] + red[2] + red[3]);
}

extern "C" __global__ void __launch_bounds__(64) final_kernel(
    const double* __restrict__ ws, float* __restrict__ out) {
  if (threadIdx.x == 0) {
    double loss = 0.0;
    for (int b = 0; b < 2; ++b) {
      double S1 = 0.0, S2 = 0.0, PC = 0.0, SP = 0.0, RS = 0.0, T1 = 0.0;
      for (int st = 0; st < 8; ++st) {
        S1 += ws[ACC_OFF(0, b, st)];
        S2 += ws[ACC_OFF(1, b, st)];
        PC += ws[ACC_OFF(2, b, st)];
        SP += ws[ACC_OFF(3, b, st)];
        RS += ws[ROI_OFF(b, st)];
        T1 += ws[T1_OFF(b, st)];
      }
      float cc = (float)(S1 / (S2 + 1e-4));
      out[1 + b] = cc;                  // NormConst
      double term1 = (cc > 1e-4f) ? T1 / (603.0 * 65536.0) : 0.0;
      float meanPrd = (float)(SP / PC);
      bool big = RS > 200.0;
      float t2 = (big && meanPrd > 30.f && cc > 10.f) ? (meanPrd - 30.f) : 0.f;
      float fact = 0.1f / (cc + 0.001f);
      float t3 = (big && meanPrd < 2.f && cc < 0.1f) ? (0.2f - meanPrd) * fact : 0.f;
      loss += term1 + (double)(t2 + t3);
    }
    out[0] = (float)loss;
  }
}

extern "C" void kernel_launch(void* const* d_in, const int* in_sizes, int n_in,
                              void* d_out, int out_size, void* d_ws, size_t ws_size,
                              hipStream_t stream) {
  (void)in_sizes; (void)n_in; (void)out_size; (void)ws_size;
  const float* Pred = (const float*)d_in[0];
  const float* GT = (const float*)d_in[1];
  const float* ROI = (const float*)d_in[2];
  float* out = (float*)d_out;
  double* ws = (double*)d_ws;

  hipMemsetAsync(d_ws, 0, 704 * sizeof(double), stream);  // striped accums
  hipLaunchKernelGGL(pass1_kernel, dim3(NLINES), dim3(256), 0, stream,
                     Pred, GT, ROI, ws);
  hipLaunchKernelGGL(pass2_kernel, dim3(NLINES), dim3(256), 0, stream,
                     Pred, GT, ROI, ws);
  hipLaunchKernelGGL(final_kernel, dim3(1), dim3(64), 0, stream, ws, out);
}